// Round 8
// baseline (2644.103 us; speedup 1.0000x reference)
//
#include <hip/hip_runtime.h>
#include <math.h>

#define HH      128
#define GHN     9
#define GWN     9
#define BATCH   4096
#define NCELL   81
#define MSAMP   16
#define THREADS 512
#define NBLK    (BATCH / MSAMP)   // 256 blocks -> 1 per CU, 8 waves
#define EPSF    1e-5f

typedef __attribute__((ext_vector_type(8))) short  bf8;     // 8 bf16 (4 VGPRs)
typedef __attribute__((ext_vector_type(4))) short  short4v; // 8 bytes
typedef __attribute__((ext_vector_type(4))) float  f32x4;

#define MFMA(a, b, c) __builtin_amdgcn_mfma_f32_16x16x32_bf16(a, b, c, 0, 0, 0)

__device__ __forceinline__ float rcp_fast(float x) { return __builtin_amdgcn_rcpf(x); }
__device__ __forceinline__ float rsq_fast(float x) { return __builtin_amdgcn_rsqf(x); }
__device__ __forceinline__ float sigm(float x)     { return rcp_fast(1.f + __expf(-x)); }
__device__ __forceinline__ float tanh_fast(float x) {
    float ax = fabsf(x);
    float t  = __expf(-2.f * ax);
    float r  = (1.f - t) * rcp_fast(1.f + t);
    return (x < 0.f) ? -r : r;
}
__device__ __forceinline__ short f2bf(float f) {        // RNE fp32->bf16
    unsigned u = __float_as_uint(f);
    u = (u + 0x7FFFu + ((u >> 16) & 1u)) >> 16;
    return (short)u;
}
__device__ __forceinline__ float bf2f(short h) {
    return __uint_as_float(((unsigned)(unsigned short)h) << 16);
}
__device__ __forceinline__ void split_bf(float f, short& hi, short& lo) {
    hi = f2bf(f);
    lo = f2bf(f - bf2f(hi));
}
__device__ __forceinline__ void store_frag4(short* hiA, short* loA, int idx, float4 v) {
    short4v h, l; short a, b;
    split_bf(v.x, a, b); h.x = a; l.x = b;
    split_bf(v.y, a, b); h.y = a; l.y = b;
    split_bf(v.z, a, b); h.z = a; l.z = b;
    split_bf(v.w, a, b); h.w = a; l.w = b;
    *(short4v*)&hiA[idx] = h;
    *(short4v*)&loA[idx] = l;
}
// frag slot for (k multiple of 4, sample m): A layout [kstep][lane=(kgrp<<4)|m][8]
__device__ __forceinline__ int frag4_idx(int k, int m) {
    return (k >> 5) * 512 + ((((k & 31) >> 3) << 4) | m) * 8 + (k & 7);
}
// barrier that does NOT drain vmcnt: LDS-release only
__device__ __forceinline__ void barrier_lgkm() {
    asm volatile("s_waitcnt lgkmcnt(0)" ::: "memory");
    __builtin_amdgcn_s_barrier();
    __builtin_amdgcn_sched_barrier(0);
}

// ---------------------------------------------------------------------------
// Build bf16 hi/lo B-fragments for all weights (unchanged from R5).
//   whB/wcB : [81][8 ntile][12 kstep][64 lane][8]
//   whhB    : [81][32 ntile][4 kstep][64 lane][8]
// ---------------------------------------------------------------------------
__global__ __launch_bounds__(256)
void k_buildw(const float* __restrict__ Wh, const float* __restrict__ Wc,
              const float* __restrict__ Whh,
              short* __restrict__ whB_hi, short* __restrict__ whB_lo,
              short* __restrict__ wcB_hi, short* __restrict__ wcB_lo,
              short* __restrict__ whhB_hi, short* __restrict__ whhB_lo)
{
    __shared__ float lw[32 * 384];
    const int u  = threadIdx.x;
    const int kc = blockIdx.x / 24;
    const int c  = blockIdx.x % 24;

    if (c < 8) {
        const int mat = c >> 2;
        const int p   = c & 3;
        const float* src = (mat ? Wc : Wh) + ((size_t)kc * 128 + 32 * p) * 384;
        #pragma unroll
        for (int it = 0; it < 12; ++it)
            ((float4*)lw)[it * 256 + u] = ((const float4*)src)[it * 256 + u];
        __syncthreads();
        short* Dhi = mat ? wcB_hi : whB_hi;
        short* Dlo = mat ? wcB_lo : whB_lo;
        #pragma unroll
        for (int it = 0; it < 6; ++it) {
            const int wd = it * 256 + u;
            const int tt = wd / 768;
            const int rm = wd - tt * 768;
            const int s  = rm >> 6;
            const int l  = rm & 63;
            const int rl = tt * 16 + (l & 15);
            const int kk = s * 32 + (l >> 4) * 8;
            const float* pr = &lw[rl * 384 + kk];
            const float4 v0 = *(const float4*)pr;
            const float4 v1 = *(const float4*)(pr + 4);
            const size_t dst = (((size_t)kc * 8 + (2 * p + tt)) * 12 + s) * 512 + l * 8;
            short4v h, lo; short a, b;
            split_bf(v0.x, a, b); h.x = a; lo.x = b;
            split_bf(v0.y, a, b); h.y = a; lo.y = b;
            split_bf(v0.z, a, b); h.z = a; lo.z = b;
            split_bf(v0.w, a, b); h.w = a; lo.w = b;
            *(short4v*)&Dhi[dst]     = h;  *(short4v*)&Dlo[dst]     = lo;
            split_bf(v1.x, a, b); h.x = a; lo.x = b;
            split_bf(v1.y, a, b); h.y = a; lo.y = b;
            split_bf(v1.z, a, b); h.z = a; lo.z = b;
            split_bf(v1.w, a, b); h.w = a; lo.w = b;
            *(short4v*)&Dhi[dst + 4] = h;  *(short4v*)&Dlo[dst + 4] = lo;
        }
    } else {
        const int cc = c - 8;
        const float* src = Whh + ((size_t)kc * 512 + 32 * cc) * 128;
        #pragma unroll
        for (int it = 0; it < 4; ++it)
            ((float4*)lw)[it * 256 + u] = ((const float4*)src)[it * 256 + u];
        __syncthreads();
        #pragma unroll
        for (int it = 0; it < 2; ++it) {
            const int wd = it * 256 + u;
            const int tt = wd >> 8;
            const int rm = wd & 255;
            const int s  = rm >> 6;
            const int l  = rm & 63;
            const int rl = tt * 16 + (l & 15);
            const int kk = s * 32 + (l >> 4) * 8;
            const float* pr = &lw[rl * 128 + kk];
            const float4 v0 = *(const float4*)pr;
            const float4 v1 = *(const float4*)(pr + 4);
            const size_t dst = (((size_t)kc * 32 + (2 * cc + tt)) * 4 + s) * 512 + l * 8;
            short4v h, lo; short a, b;
            split_bf(v0.x, a, b); h.x = a; lo.x = b;
            split_bf(v0.y, a, b); h.y = a; lo.y = b;
            split_bf(v0.z, a, b); h.z = a; lo.z = b;
            split_bf(v0.w, a, b); h.w = a; lo.w = b;
            *(short4v*)&whhB_hi[dst]     = h;  *(short4v*)&whhB_lo[dst]     = lo;
            split_bf(v1.x, a, b); h.x = a; lo.x = b;
            split_bf(v1.y, a, b); h.y = a; lo.y = b;
            split_bf(v1.z, a, b); h.z = a; lo.z = b;
            split_bf(v1.w, a, b); h.w = a; lo.w = b;
            *(short4v*)&whhB_hi[dst + 4] = h;  *(short4v*)&whhB_lo[dst + 4] = lo;
        }
    }
}

// ---------------------------------------------------------------------------
// MFMA lattice: 256 blocks x 16 samples, 512 threads (8 waves).
// 2 raw lgkm-barriers/cell; vmcnt(0) only at row ends. preLN: wave w =
// (mat=w&1, tiles w>>1 and (w>>1)+4), 3-pass split, writes RAW d0 + LN
// partials. Gates: all 8 waves, normalize ph inline from raw, 3-pass;
// pointwise normalizes pc inline. Next-cell g0/up prefetch in registers.
// ---------------------------------------------------------------------------
__global__ __launch_bounds__(THREADS, 2)
void k_lattice(const float* __restrict__ x, const float* __restrict__ h_ext,
               const float* __restrict__ c_ext, const float* __restrict__ h_g0,
               const float* __restrict__ c_g0,
               const short* __restrict__ whB_hi, const short* __restrict__ whB_lo,
               const short* __restrict__ wcB_hi, const short* __restrict__ wcB_lo,
               const short* __restrict__ whhB_hi, const short* __restrict__ whhB_lo,
               const float* __restrict__ bh, const float* __restrict__ bc,
               const float* __restrict__ lnh_g, const float* __restrict__ lnh_b,
               const float* __restrict__ lnc_g, const float* __restrict__ lnc_b,
               const float* __restrict__ W_ih, const float* __restrict__ b_ih,
               const float* __restrict__ b_hh,
               float* __restrict__ hrowB, float* __restrict__ crowB,
               float* __restrict__ zout)
{
    __shared__ __align__(16) short sAH_hi[12 * 512], sAH_lo[12 * 512];
    __shared__ __align__(16) short sAC_hi[12 * 512], sAC_lo[12 * 512];   // 48KB
    __shared__ float phRaw[16 * 132], pcRaw[16 * 132];                   // 16.5KB
    __shared__ float part_s[16 * 16], part_q[16 * 16];                   // 2KB  [mat*8+tile][sample]
    __shared__ float xsArr[16 * NCELL];                                  // 5.2KB

    const int t    = threadIdx.x;
    const int base = blockIdx.x * MSAMP;
    const int lane = t & 63;
    const int w    = t >> 6;         // wave 0..7
    const int cL   = lane & 15;
    const int gL   = lane >> 4;

    // preLN roles
    const int mat = w & 1;           // 0=H 1=C
    const int tp  = w >> 1;          // 0..3
    const int t0  = tp, t1 = tp + 4;
    const int f0  = t0 * 16 + cL, f1 = t1 * 16 + cL;
    // gates roles
    const int q0  = w * 16 + cL;
    // build roles
    const int m_b = t >> 5;          // 0..15 sample
    const int f4  = (t & 31) * 4;    // feature quad

    for (int idx = t; idx < MSAMP * NCELL; idx += THREADS) {
        const int m = idx / NCELL;
        const int cc = idx - m * NCELL;
        xsArr[idx] = x[(size_t)(base + m) * NCELL + cc];
    }
    const float4 z4 = make_float4(0.f, 0.f, 0.f, 0.f);
    float4 pfUH = z4, pfUC = z4, pfPH = z4, pfPC = z4;
    bool havePf = false;

    #pragma unroll 1
    for (int i = 0; i < GHN; ++i) {
      #pragma unroll 1
      for (int j = 0; j < GWN; ++j) {
        const int k = i * GWN + j;

        // ---------------- build: up/prev bands (+left at j==0) ---------------
        {
            float4 uh, uc, pv, qv;
            if (havePf) { uh = pfUH; uc = pfUC; pv = pfPH; qv = pfPC; }
            else {
                if (i > 0) {
                    uh = *(const float4*)&hrowB[((size_t)(base + m_b) * GWN + j) * HH + f4];
                    uc = *(const float4*)&crowB[((size_t)(base + m_b) * GWN + j) * HH + f4];
                } else { uh = z4; uc = z4; }
                pv = *(const float4*)&h_g0[((size_t)k * BATCH + base + m_b) * HH + f4];
                qv = *(const float4*)&c_g0[((size_t)k * BATCH + base + m_b) * HH + f4];
            }
            if (j == 0) {
                float4 lh = z4, lc = z4;
                if (i == 0) {
                    lh = *(const float4*)&h_ext[(size_t)(base + m_b) * HH + f4];
                    lc = *(const float4*)&c_ext[(size_t)(base + m_b) * HH + f4];
                }
                store_frag4(sAH_hi, sAH_lo, frag4_idx(f4, m_b), lh);
                store_frag4(sAC_hi, sAC_lo, frag4_idx(f4, m_b), lc);
            }
            store_frag4(sAH_hi, sAH_lo, frag4_idx(128 + f4, m_b), uh);
            store_frag4(sAC_hi, sAC_lo, frag4_idx(128 + f4, m_b), uc);
            store_frag4(sAH_hi, sAH_lo, frag4_idx(256 + f4, m_b), pv);
            store_frag4(sAC_hi, sAC_lo, frag4_idx(256 + f4, m_b), qv);

            // prefetch next cell (same row only; row crossings reload after vmdrain)
            if (j < GWN - 1) {
                if (i > 0) {
                    pfUH = *(const float4*)&hrowB[((size_t)(base + m_b) * GWN + j + 1) * HH + f4];
                    pfUC = *(const float4*)&crowB[((size_t)(base + m_b) * GWN + j + 1) * HH + f4];
                } else { pfUH = z4; pfUC = z4; }
                pfPH = *(const float4*)&h_g0[((size_t)(k + 1) * BATCH + base + m_b) * HH + f4];
                pfPC = *(const float4*)&c_g0[((size_t)(k + 1) * BATCH + base + m_b) * HH + f4];
                havePf = true;
            } else havePf = false;
        }

        // hoist preLN ks=0 weights above B1 (ride across the barrier)
        const short* Ahi = mat ? sAC_hi : sAH_hi;
        const short* Alo = mat ? sAC_lo : sAH_lo;
        const short* Bhi = (mat ? wcB_hi : whB_hi) + (size_t)k * 49152;
        const short* Blo = (mat ? wcB_lo : whB_lo) + (size_t)k * 49152;
        const bf8 hw0h = *(const bf8*)&Bhi[(t0 * 12) * 512 + lane * 8];
        const bf8 hw0l = *(const bf8*)&Blo[(t0 * 12) * 512 + lane * 8];
        const bf8 hw1h = *(const bf8*)&Bhi[(t1 * 12) * 512 + lane * 8];
        const bf8 hw1l = *(const bf8*)&Blo[(t1 * 12) * 512 + lane * 8];

        barrier_lgkm();   // B1: frags visible; vmcnt NOT drained

        // ---------------- preLN MFMA: 2 N-tiles, 3-pass ----------------------
        f32x4 d0 = {0.f, 0.f, 0.f, 0.f}, d1 = {0.f, 0.f, 0.f, 0.f};
        {
            const bf8 ah = *(const bf8*)&Ahi[lane * 8];
            const bf8 al = *(const bf8*)&Alo[lane * 8];
            d0 = MFMA(al, hw0h, d0); d0 = MFMA(ah, hw0l, d0); d0 = MFMA(ah, hw0h, d0);
            d1 = MFMA(al, hw1h, d1); d1 = MFMA(ah, hw1l, d1); d1 = MFMA(ah, hw1h, d1);
        }
        #pragma unroll 4
        for (int ks = 1; ks < 12; ++ks) {
            const bf8 ah  = *(const bf8*)&Ahi[ks * 512 + lane * 8];
            const bf8 al  = *(const bf8*)&Alo[ks * 512 + lane * 8];
            const bf8 b0h = *(const bf8*)&Bhi[(t0 * 12 + ks) * 512 + lane * 8];
            const bf8 b0l = *(const bf8*)&Blo[(t0 * 12 + ks) * 512 + lane * 8];
            const bf8 b1h = *(const bf8*)&Bhi[(t1 * 12 + ks) * 512 + lane * 8];
            const bf8 b1l = *(const bf8*)&Blo[(t1 * 12 + ks) * 512 + lane * 8];
            d0 = MFMA(al, b0h, d0); d0 = MFMA(ah, b0l, d0); d0 = MFMA(ah, b0h, d0);
            d1 = MFMA(al, b1h, d1); d1 = MFMA(ah, b1l, d1); d1 = MFMA(ah, b1h, d1);
        }
        {
            const float* bias = mat ? bc : bh;
            d0 += bias[k * HH + f0];
            d1 += bias[k * HH + f1];
        }
        // LN partials (16-lane feature reduce) + raw writes
        {
            float ps0[4], pq0[4], ps1[4], pq1[4];
            #pragma unroll
            for (int r = 0; r < 4; ++r) {
                ps0[r] = d0[r]; pq0[r] = d0[r] * d0[r];
                ps1[r] = d1[r]; pq1[r] = d1[r] * d1[r];
            }
            #pragma unroll
            for (int msk = 1; msk < 16; msk <<= 1) {
                #pragma unroll
                for (int r = 0; r < 4; ++r) {
                    ps0[r] += __shfl_xor(ps0[r], msk);
                    pq0[r] += __shfl_xor(pq0[r], msk);
                    ps1[r] += __shfl_xor(ps1[r], msk);
                    pq1[r] += __shfl_xor(pq1[r], msk);
                }
            }
            if (cL == 0) {
                #pragma unroll
                for (int r = 0; r < 4; ++r) {
                    const int s = gL * 4 + r;
                    part_s[(mat * 8 + t0) * 16 + s] = ps0[r];
                    part_q[(mat * 8 + t0) * 16 + s] = pq0[r];
                    part_s[(mat * 8 + t1) * 16 + s] = ps1[r];
                    part_q[(mat * 8 + t1) * 16 + s] = pq1[r];
                }
            }
            float* RW = mat ? pcRaw : phRaw;
            #pragma unroll
            for (int r = 0; r < 4; ++r) {
                const int s = gL * 4 + r;
                RW[s * 132 + f0] = d0[r];
                RW[s * 132 + f1] = d1[r];
            }
        }

        // hoist gates ks=0 weights above B2
        const short* GBhi = whhB_hi + (size_t)k * 65536;
        const short* GBlo = whhB_lo + (size_t)k * 65536;
        const bf8 gw0h = *(const bf8*)&GBhi[((w     ) * 4) * 512 + lane * 8];
        const bf8 gw0l = *(const bf8*)&GBlo[((w     ) * 4) * 512 + lane * 8];
        const bf8 gw1h = *(const bf8*)&GBhi[((w +  8) * 4) * 512 + lane * 8];
        const bf8 gw1l = *(const bf8*)&GBlo[((w +  8) * 4) * 512 + lane * 8];
        const bf8 gw2h = *(const bf8*)&GBhi[((w + 16) * 4) * 512 + lane * 8];
        const bf8 gw2l = *(const bf8*)&GBlo[((w + 16) * 4) * 512 + lane * 8];
        const bf8 gw3h = *(const bf8*)&GBhi[((w + 24) * 4) * 512 + lane * 8];
        const bf8 gw3l = *(const bf8*)&GBlo[((w + 24) * 4) * 512 + lane * 8];

        barrier_lgkm();   // B2: raw+partials visible; weights in flight

        // ---------------- gates: inline-normalized A, 3-pass ----------------
        f32x4 ga0 = {0.f,0.f,0.f,0.f}, ga1 = ga0, ga2 = ga0, ga3 = ga0;
        float muH, rsH;
        {
            float ts = 0.f, tq = 0.f;
            #pragma unroll
            for (int pp = 0; pp < 8; ++pp) { ts += part_s[pp * 16 + cL]; tq += part_q[pp * 16 + cL]; }
            muH = ts * (1.f / HH);
            rsH = rsq_fast(tq * (1.f / HH) - muH * muH + EPSF);
        }
        #pragma unroll
        for (int ks = 0; ks < 4; ++ks) {
            const float* pr = &phRaw[cL * 132 + ks * 32 + gL * 8];
            const float4 va = *(const float4*)pr;
            const float4 vb = *(const float4*)(pr + 4);
            const int fb = k * HH + ks * 32 + gL * 8;
            const float4 lg0 = *(const float4*)&lnh_g[fb];
            const float4 lg1 = *(const float4*)&lnh_g[fb + 4];
            const float4 lb0 = *(const float4*)&lnh_b[fb];
            const float4 lb1 = *(const float4*)&lnh_b[fb + 4];
            bf8 ah, al;
            {
                short hi, lo; float vv;
                vv = (va.x - muH) * rsH * lg0.x + lb0.x; split_bf(vv, hi, lo); ah[0] = hi; al[0] = lo;
                vv = (va.y - muH) * rsH * lg0.y + lb0.y; split_bf(vv, hi, lo); ah[1] = hi; al[1] = lo;
                vv = (va.z - muH) * rsH * lg0.z + lb0.z; split_bf(vv, hi, lo); ah[2] = hi; al[2] = lo;
                vv = (va.w - muH) * rsH * lg0.w + lb0.w; split_bf(vv, hi, lo); ah[3] = hi; al[3] = lo;
                vv = (vb.x - muH) * rsH * lg1.x + lb1.x; split_bf(vv, hi, lo); ah[4] = hi; al[4] = lo;
                vv = (vb.y - muH) * rsH * lg1.y + lb1.y; split_bf(vv, hi, lo); ah[5] = hi; al[5] = lo;
                vv = (vb.z - muH) * rsH * lg1.z + lb1.z; split_bf(vv, hi, lo); ah[6] = hi; al[6] = lo;
                vv = (vb.w - muH) * rsH * lg1.w + lb1.w; split_bf(vv, hi, lo); ah[7] = hi; al[7] = lo;
            }
            bf8 b0h, b0l, b1h, b1l, b2h, b2l, b3h, b3l;
            if (ks == 0) {
                b0h = gw0h; b0l = gw0l; b1h = gw1h; b1l = gw1l;
                b2h = gw2h; b2l = gw2l; b3h = gw3h; b3l = gw3l;
            } else {
                b0h = *(const bf8*)&GBhi[((w     ) * 4 + ks) * 512 + lane * 8];
                b0l = *(const bf8*)&GBlo[((w     ) * 4 + ks) * 512 + lane * 8];
                b1h = *(const bf8*)&GBhi[((w +  8) * 4 + ks) * 512 + lane * 8];
                b1l = *(const bf8*)&GBlo[((w +  8) * 4 + ks) * 512 + lane * 8];
                b2h = *(const bf8*)&GBhi[((w + 16) * 4 + ks) * 512 + lane * 8];
                b2l = *(const bf8*)&GBlo[((w + 16) * 4 + ks) * 512 + lane * 8];
                b3h = *(const bf8*)&GBhi[((w + 24) * 4 + ks) * 512 + lane * 8];
                b3l = *(const bf8*)&GBlo[((w + 24) * 4 + ks) * 512 + lane * 8];
            }
            ga0 = MFMA(al, b0h, ga0); ga0 = MFMA(ah, b0l, ga0); ga0 = MFMA(ah, b0h, ga0);
            ga1 = MFMA(al, b1h, ga1); ga1 = MFMA(ah, b1l, ga1); ga1 = MFMA(ah, b1h, ga1);
            ga2 = MFMA(al, b2h, ga2); ga2 = MFMA(ah, b2l, ga2); ga2 = MFMA(ah, b2h, ga2);
            ga3 = MFMA(al, b3h, ga3); ga3 = MFMA(ah, b3l, ga3); ga3 = MFMA(ah, b3h, ga3);
        }

        // ---------------- pointwise (inline pc normalize) --------------------
        {
            const float gcq = lnc_g[k * HH + q0], ecq = lnc_b[k * HH + q0];
            const float wi0 = W_ih[k * 512 + q0      ];
            const float wi1 = W_ih[k * 512 + q0 + 128];
            const float wi2 = W_ih[k * 512 + q0 + 256];
            const float wi3 = W_ih[k * 512 + q0 + 384];
            const float bs0 = b_ih[k * 512 + q0      ] + b_hh[k * 512 + q0      ];
            const float bs1 = b_ih[k * 512 + q0 + 128] + b_hh[k * 512 + q0 + 128];
            const float bs2 = b_ih[k * 512 + q0 + 256] + b_hh[k * 512 + q0 + 256];
            const float bs3 = b_ih[k * 512 + q0 + 384] + b_hh[k * 512 + q0 + 384];
            #pragma unroll
            for (int r = 0; r < 4; ++r) {
                const int s = gL * 4 + r;
                const int b = base + s;
                float ts = 0.f, tq = 0.f;
                #pragma unroll
                for (int pp = 8; pp < 16; ++pp) { ts += part_s[pp * 16 + s]; tq += part_q[pp * 16 + s]; }
                const float muC = ts * (1.f / HH);
                const float rsC = rsq_fast(tq * (1.f / HH) - muC * muC + EPSF);
                const float pcv = (pcRaw[s * 132 + q0] - muC) * rsC * gcq + ecq;
                const float xv  = xsArr[s * NCELL + k];
                const float gi_ = ga0[r] + bs0 + wi0 * xv;
                const float gf_ = ga1[r] + bs1 + wi1 * xv;
                const float gg_ = ga2[r] + bs2 + wi2 * xv;
                const float go_ = ga3[r] + bs3 + wi3 * xv;
                const float cn = sigm(gf_) * pcv + sigm(gi_) * tanh_fast(gg_);
                const float hn = sigm(go_) * tanh_fast(cn);
                if (k == NCELL - 1) {
                    zout[(size_t)b * 256 + q0]       = hn + h_ext[(size_t)b * HH + q0];
                    zout[(size_t)b * 256 + 128 + q0] = cn + c_ext[(size_t)b * HH + q0];
                } else {
                    if (j < GWN - 1) {
                        const int ei = (q0 >> 5) * 512 + ((((q0 & 31) >> 3) << 4) | s) * 8 + (q0 & 7);
                        short hi, lo;
                        split_bf(hn, hi, lo); sAH_hi[ei] = hi; sAH_lo[ei] = lo;
                        split_bf(cn, hi, lo); sAC_hi[ei] = hi; sAC_lo[ei] = lo;
                    }
                    if (i < GHN - 1) {
                        hrowB[((size_t)b * GWN + j) * HH + q0] = hn;
                        crowB[((size_t)b * GWN + j) * HH + q0] = cn;
                    }
                }
            }
        }
        // row boundary: order hrow/crow stores before next row's loads
        if (j == GWN - 1) asm volatile("s_waitcnt vmcnt(0)" ::: "memory");
      }
    }
}

// ---------------------------------------------------------------------------
// fc1: y1 = z @ fc1_W^T + b  [4096,256], fused column sum/sumsq atomics
// ---------------------------------------------------------------------------
__global__ __launch_bounds__(256)
void k_fc1(const float* __restrict__ z, const float* __restrict__ W,
           const float* __restrict__ bias, float* __restrict__ y1,
           float* __restrict__ s1, float* __restrict__ q1)
{
    __shared__ float at[256 * 16];
    const int t   = threadIdx.x;
    const int row = t & 15;
    const int cg  = t >> 4;
    const int rb  = blockIdx.x * 16;
    {
        const float* zr = z + (size_t)(rb + row) * 256 + cg * 16;
        #pragma unroll
        for (int v = 0; v < 4; ++v) {
            const float4 zz = *(const float4*)(zr + v * 4);
            const int kk = cg * 16 + v * 4;
            at[(kk + 0) * 16 + row] = zz.x;
            at[(kk + 1) * 16 + row] = zz.y;
            at[(kk + 2) * 16 + row] = zz.z;
            at[(kk + 3) * 16 + row] = zz.w;
        }
    }
    __syncthreads();
    const int c0 = cg * 16;
    float acc[16];
    #pragma unroll
    for (int c = 0; c < 16; ++c) acc[c] = bias[c0 + c];
    for (int kb = 0; kb < 64; ++kb) {
        const float a0 = at[(4 * kb + 0) * 16 + row];
        const float a1 = at[(4 * kb + 1) * 16 + row];
        const float a2 = at[(4 * kb + 2) * 16 + row];
        const float a3 = at[(4 * kb + 3) * 16 + row];
        #pragma unroll
        for (int c = 0; c < 16; ++c) {
            const float4 wv = *(const float4*)&W[(size_t)(c0 + c) * 256 + 4 * kb];
            acc[c] += a0 * wv.x + a1 * wv.y + a2 * wv.z + a3 * wv.w;
        }
    }
    {
        float* yr = y1 + (size_t)(rb + row) * 256 + c0;
        #pragma unroll
        for (int v = 0; v < 4; ++v)
            *(float4*)(yr + v * 4) = make_float4(acc[4*v], acc[4*v+1], acc[4*v+2], acc[4*v+3]);
    }
    #pragma unroll
    for (int c = 0; c < 16; ++c) {
        float s = acc[c], sq = acc[c] * acc[c];
        s += __shfl_xor(s, 1); sq += __shfl_xor(sq, 1);
        s += __shfl_xor(s, 2); sq += __shfl_xor(sq, 2);
        s += __shfl_xor(s, 4); sq += __shfl_xor(sq, 4);
        s += __shfl_xor(s, 8); sq += __shfl_xor(sq, 8);
        if (row == 0) { atomicAdd(&s1[c0 + c], s); atomicAdd(&q1[c0 + c], sq); }
    }
}

// ---------------------------------------------------------------------------
// fc2: y2 = relu(bn1(y1)) @ fc2_W^T + b  [4096,128], fused stats
// ---------------------------------------------------------------------------
__global__ __launch_bounds__(256)
void k_fc2(const float* __restrict__ y1, const float* __restrict__ W,
           const float* __restrict__ bias,
           const float* __restrict__ s1, const float* __restrict__ q1,
           const float* __restrict__ g1, const float* __restrict__ b1,
           float* __restrict__ y2, float* __restrict__ s2, float* __restrict__ q2)
{
    __shared__ float at[256 * 16];
    __shared__ float scale[256], shift[256];
    const int t = threadIdx.x;
    {
        const float mu  = s1[t] * (1.f / BATCH);
        const float var = q1[t] * (1.f / BATCH) - mu * mu;
        const float sc  = g1[t] * rsq_fast(var + EPSF);
        scale[t] = sc;
        shift[t] = b1[t] - mu * sc;
    }
    __syncthreads();
    const int row = t & 15;
    const int cg  = t >> 4;
    const int rb  = blockIdx.x * 16;
    {
        const float* yr = y1 + (size_t)(rb + row) * 256 + cg * 16;
        #pragma unroll
        for (int v = 0; v < 4; ++v) {
            const float4 zz = *(const float4*)(yr + v * 4);
            const int kk = cg * 16 + v * 4;
            at[(kk + 0) * 16 + row] = fmaxf(zz.x * scale[kk + 0] + shift[kk + 0], 0.f);
            at[(kk + 1) * 16 + row] = fmaxf(zz.y * scale[kk + 1] + shift[kk + 1], 0.f);
            at[(kk + 2) * 16 + row] = fmaxf(zz.z * scale[kk + 2] + shift[kk + 2], 0.f);
            at[(kk + 3) * 16 + row] = fmaxf(zz.w * scale[kk + 3] + shift[kk + 3], 0.f);
        }
    }
    __syncthreads();
    const int c0 = cg * 8;
    float acc[8];
    #pragma unroll
    for (int c = 0; c < 8; ++c) acc[c] = bias[c0 + c];
    for (int kb = 0; kb < 64; ++kb) {
        const float a0 = at[(4 * kb + 0) * 16 + row];
        const float a1 = at[(4 * kb + 1) * 16 + row];
        const float a2 = at[(4 * kb + 2) * 16 + row];
        const float a3 = at[(4 * kb + 3) * 16 + row];
        #pragma unroll
        for (int c = 0; c < 8; ++c) {
            const float4 wv = *(const float4*)&W[(size_t)(c0 + c) * 256 + 4 * kb];
            acc[c] += a0 * wv.x + a1 * wv.y + a2 * wv.z + a3 * wv.w;
        }
    }
    {
        float* yr = y2 + (size_t)(rb + row) * 128 + c0;
        *(float4*)(yr)     = make_float4(acc[0], acc[1], acc[2], acc[3]);
        *(float4*)(yr + 4) = make_float4(acc[4], acc[5], acc[6], acc[7]);
    }
    #pragma unroll
    for (int c = 0; c < 8; ++c) {
        float s = acc[c], sq = acc[c] * acc[c];
        s += __shfl_xor(s, 1); sq += __shfl_xor(sq, 1);
        s += __shfl_xor(s, 2); sq += __shfl_xor(sq, 2);
        s += __shfl_xor(s, 4); sq += __shfl_xor(sq, 4);
        s += __shfl_xor(s, 8); sq += __shfl_xor(sq, 8);
        if (row == 0) { atomicAdd(&s2[c0 + c], s); atomicAdd(&q2[c0 + c], sq); }
    }
}

// ---------------------------------------------------------------------------
// fc3: y3 = relu(bn2(y2)) @ fc3_W^T + b  [4096,1], fused scalar stats
// ---------------------------------------------------------------------------
__global__ __launch_bounds__(256)
void k_fc3(const float* __restrict__ y2, const float* __restrict__ W3,
           const float* __restrict__ b3,
           const float* __restrict__ s2, const float* __restrict__ q2,
           const float* __restrict__ g2, const float* __restrict__ b2,
           float* __restrict__ y3, float* __restrict__ s3, float* __restrict__ q3)
{
    __shared__ float scale[128], shift[128], w3s[128];
    const int t = threadIdx.x;
    if (t < 128) {
        const float mu  = s2[t] * (1.f / BATCH);
        const float var = q2[t] * (1.f / BATCH) - mu * mu;
        const float sc  = g2[t] * rsq_fast(var + EPSF);
        scale[t] = sc;
        shift[t] = b2[t] - mu * sc;
        w3s[t]   = W3[t];
    }
    __syncthreads();
    const int r = blockIdx.x * 256 + t;
    float acc = b3[0];
    const float* yr = y2 + (size_t)r * 128;
    for (int kb = 0; kb < 32; ++kb) {
        const float4 v = *(const float4*)(yr + 4 * kb);
        const int kk = 4 * kb;
        acc += fmaxf(v.x * scale[kk + 0] + shift[kk + 0], 0.f) * w3s[kk + 0];
        acc += fmaxf(v.y * scale[kk + 1] + shift[kk + 1], 0.f) * w3s[kk + 1];
        acc += fmaxf(v.z * scale[kk + 2] + shift[kk + 2], 0.f) * w3s[kk + 2];
        acc += fmaxf(v.w * scale[kk + 3] + shift[kk + 3], 0.f) * w3s[kk + 3];
    }
    y3[r] = acc;
    float s = acc, sq = acc * acc;
    #pragma unroll
    for (int d = 1; d < 64; d <<= 1) { s += __shfl_xor(s, d); sq += __shfl_xor(sq, d); }
    if ((t & 63) == 0) { atomicAdd(&s3[0], s); atomicAdd(&q3[0], sq); }
}

// ---------------------------------------------------------------------------
// out = sigmoid(bn_out(y3))
// ---------------------------------------------------------------------------
__global__ __launch_bounds__(256)
void k_out(const float* __restrict__ y3,
           const float* __restrict__ s3, const float* __restrict__ q3,
           const float* __restrict__ g, const float* __restrict__ b,
           float* __restrict__ out)
{
    const int r = blockIdx.x * 256 + threadIdx.x;
    const float mu  = s3[0] * (1.f / BATCH);
    const float var = q3[0] * (1.f / BATCH) - mu * mu;
    const float sc  = g[0] * rsq_fast(var + EPSF);
    out[r] = sigm((y3[r] - mu) * sc + b[0]);
}

// ---------------------------------------------------------------------------
extern "C" void kernel_launch(void* const* d_in, const int* in_sizes, int n_in,
                              void* d_out, int out_size, void* d_ws, size_t ws_size,
                              hipStream_t stream)
{
    const float* x     = (const float*)d_in[0];
    const float* h_ext = (const float*)d_in[1];
    const float* c_ext = (const float*)d_in[2];
    const float* h_g0  = (const float*)d_in[3];
    const float* c_g0  = (const float*)d_in[4];
    const float* Wh    = (const float*)d_in[5];
    const float* bh    = (const float*)d_in[6];
    const float* Wc    = (const float*)d_in[7];
    const float* bc    = (const float*)d_in[8];
    const float* lnh_g = (const float*)d_in[9];
    const float* lnh_b = (const float*)d_in[10];
    const float* lnc_g = (const float*)d_in[11];
    const float* lnc_b = (const float*)d_in[12];
    const float* W_ih  = (const float*)d_in[13];
    const float* b_ih  = (const float*)d_in[14];
    const float* W_hh  = (const float*)d_in[15];
    const float* b_hh  = (const float*)d_in[16];
    const float* fc1_W = (const float*)d_in[17];
    const float* fc1_b = (const float*)d_in[18];
    const float* bn1_g = (const float*)d_in[19];
    const float* bn1_b = (const float*)d_in[20];
    const float* fc2_W = (const float*)d_in[21];
    const float* fc2_b = (const float*)d_in[22];
    const float* bn2_g = (const float*)d_in[23];
    const float* bn2_b = (const float*)d_in[24];
    const float* fc3_W = (const float*)d_in[25];
    const float* fc3_b = (const float*)d_in[26];
    const float* bno_g = (const float*)d_in[27];
    const float* bno_b = (const float*)d_in[28];

    // workspace layout
    short* whB_hi  = (short*)d_ws;                    // 81*8*12*512 = 3,981,312
    short* whB_lo  = whB_hi  + 3981312;
    short* wcB_hi  = whB_lo  + 3981312;
    short* wcB_lo  = wcB_hi  + 3981312;
    short* whhB_hi = wcB_lo  + 3981312;               // 81*32*4*512 = 5,308,416
    short* whhB_lo = whhB_hi + 5308416;
    float* hrow = (float*)(whhB_lo + 5308416);        // 4096*9*128
    float* crow = hrow + 4718592;
    float* z    = crow + 4718592;                     // 4096*256
    float* y1   = z    + 1048576;
    float* y2   = y1   + 1048576;
    float* y3   = y2   + 524288;
    float* st   = y3   + 4096;
    float* s1 = st;        float* q1 = s1 + 256;
    float* s2 = q1 + 256;  float* q2 = s2 + 128;
    float* s3 = q2 + 128;  float* q3 = s3 + 1;

    hipMemsetAsync(st, 0, 770 * sizeof(float), stream);
    hipLaunchKernelGGL(k_buildw, dim3(81 * 24), dim3(256), 0, stream,
                       Wh, Wc, W_hh, whB_hi, whB_lo, wcB_hi, wcB_lo, whhB_hi, whhB_lo);
    hipLaunchKernelGGL(k_lattice, dim3(NBLK), dim3(THREADS), 0, stream,
                       x, h_ext, c_ext, h_g0, c_g0,
                       whB_hi, whB_lo, wcB_hi, wcB_lo, whhB_hi, whhB_lo,
                       bh, bc, lnh_g, lnh_b, lnc_g, lnc_b, W_ih, b_ih, b_hh,
                       hrow, crow, z);
    hipLaunchKernelGGL(k_fc1, dim3(256), dim3(256), 0, stream, z, fc1_W, fc1_b, y1, s1, q1);
    hipLaunchKernelGGL(k_fc2, dim3(256), dim3(256), 0, stream,
                       y1, fc2_W, fc2_b, s1, q1, bn1_g, bn1_b, y2, s2, q2);
    hipLaunchKernelGGL(k_fc3, dim3(16), dim3(256), 0, stream,
                       y2, fc3_W, fc3_b, s2, q2, bn2_g, bn2_b, y3, s3, q3);
    hipLaunchKernelGGL(k_out, dim3(16), dim3(256), 0, stream,
                       y3, s3, q3, bno_g, bno_b, (float*)d_out);
}